// Round 2
// baseline (1583.396 us; speedup 1.0000x reference)
//
#include <hip/hip_runtime.h>

// ---------------------------------------------------------------------------
// Encoder_18365280157999: GCN-VGAE encoder on MI355X.
//   h0 = relu(x @ w_dense + b_dense)
//   A1 = Agg(h0); h1 = A1 @ w_enc + b_enc          (Agg commutes with matmul)
//   A2 = Agg(h1); mu = A2 @ w_mu + b_mu; logstd = A2 @ w_logstd + b_logstd
// Agg(M)[c] = dinv[c] * ( sum_{e: col=c} dinv[row_e]*ew_e*M[row_e] + dinv[c]*M[c] )
//
// NOTE: edge_index arrives as int32 (harness converts all integer inputs to
// int32; JAX x64 is disabled anyway). Reading it as int64 was the R1 crash.
//
// Memory plan: d_out (n*256 floats = 102.4 MB) doubles as the h0/h1 buffer;
// d_ws holds CSR arrays (~14.5 MB) + one n*256 A-buffer (102.4 MB) ≈ 117 MB.
//   matmul x -> d_out (h0)
//   spmm  d_out -> bufA (A1)
//   matmul bufA -> d_out (h1)
//   spmm  d_out -> bufA (A2)
//   matmul bufA -> d_out[0:n*128] (mu), d_out[n*128:] (logstd)
// ---------------------------------------------------------------------------

__global__ __launch_bounds__(256) void init_kernel(float* deg, int* counts, int n) {
    int i = blockIdx.x * 256 + threadIdx.x;
    if (i < n) { deg[i] = 1.0f; counts[i] = 0; }
}

__global__ __launch_bounds__(256) void edge_count_kernel(const int* __restrict__ col,
                                                         const float* __restrict__ ew,
                                                         float* __restrict__ deg,
                                                         int* __restrict__ counts, int E) {
    int e = blockIdx.x * 256 + threadIdx.x;
    if (e < E) {
        int c = col[e];
        atomicAdd(&deg[c], ew[e]);
        atomicAdd(&counts[c], 1);
    }
}

__global__ __launch_bounds__(256) void dinv_kernel(float* deg, int n) {
    int i = blockIdx.x * 256 + threadIdx.x;
    if (i < n) deg[i] = rsqrtf(deg[i]);  // deg >= 1 always (self-loop weight 1)
}

// Single-block sequential-chunk exclusive scan over counts[n] -> offsets[n+1],
// also seeds cursor[] = offsets[] for the fill pass.
__global__ __launch_bounds__(1024) void scan_kernel(const int* __restrict__ counts,
                                                    int* __restrict__ offsets,
                                                    int* __restrict__ cursor, int n) {
    __shared__ int tmp[1024];
    __shared__ int carry_s;
    int tid = threadIdx.x;
    if (tid == 0) carry_s = 0;
    __syncthreads();
    for (int base = 0; base < n; base += 1024) {
        int i = base + tid;
        int v = (i < n) ? counts[i] : 0;
        tmp[tid] = v;
        __syncthreads();
        for (int off = 1; off < 1024; off <<= 1) {
            int t = 0;
            if (tid >= off) t = tmp[tid - off];
            __syncthreads();
            if (tid >= off) tmp[tid] += t;
            __syncthreads();
        }
        int incl = tmp[tid];
        int carry = carry_s;
        int total = tmp[1023];
        int excl = carry + incl - v;
        if (i < n) { offsets[i] = excl; cursor[i] = excl; }
        __syncthreads();
        if (tid == 0) carry_s = carry + total;
        __syncthreads();
    }
    if (tid == 0) offsets[n] = carry_s;
}

__global__ __launch_bounds__(256) void fill_kernel(const int* __restrict__ row,
                                                   const int* __restrict__ col,
                                                   const float* __restrict__ ew,
                                                   const float* __restrict__ dinv,
                                                   int* __restrict__ cursor,
                                                   int* __restrict__ srow,
                                                   float* __restrict__ sval, int E) {
    int e = blockIdx.x * 256 + threadIdx.x;
    if (e < E) {
        int c = col[e];
        int r = row[e];
        int pos = atomicAdd(&cursor[c], 1);
        srow[pos] = r;
        sval[pos] = dinv[r] * ew[e];  // final multiply by dinv[c] in spmm epilogue
    }
}

// out[c] = dinv[c] * ( sum_e sval_e * h[srow_e] + dinv[c]*h[c] ), 256-wide rows.
// One wave (64 lanes x float4) per destination node; 4 waves per block.
__global__ __launch_bounds__(256) void spmm_kernel(const float* __restrict__ h,
                                                   const int* __restrict__ srow,
                                                   const float* __restrict__ sval,
                                                   const int* __restrict__ offsets,
                                                   const float* __restrict__ dinv,
                                                   float* __restrict__ out, int n) {
    int wave = threadIdx.x >> 6;
    int lane = threadIdx.x & 63;
    int c = blockIdx.x * 4 + wave;
    if (c >= n) return;
    const float4* __restrict__ h4 = (const float4*)h;
    float di = dinv[c];
    int beg = offsets[c], end = offsets[c + 1];
    float4 v = h4[(size_t)c * 64 + lane];
    float ax = di * v.x, ay = di * v.y, az = di * v.z, aw = di * v.w;
    for (int e = beg; e < end; ++e) {
        int r = srow[e];
        float s = sval[e];
        float4 u = h4[(size_t)r * 64 + lane];
        ax += s * u.x; ay += s * u.y; az += s * u.z; aw += s * u.w;
    }
    float4 o;
    o.x = di * ax; o.y = di * ay; o.z = di * az; o.w = di * aw;
    ((float4*)out)[(size_t)c * 64 + lane] = o;
}

// C[n x M] = A[n x 256] @ W[256 x M] + bias, optional relu. M % 64 == 0.
// 64x64 tile per 256-thread block, 4x4 per thread, K-chunks of 16 via LDS.
__global__ __launch_bounds__(256) void matmul_kernel(const float* __restrict__ A,
                                                     const float* __restrict__ W,
                                                     const float* __restrict__ bias,
                                                     float* __restrict__ out,
                                                     int n, int M, int relu) {
    __shared__ float As[16][68];  // [k][row], +4 pad keeps float4 alignment
    __shared__ float Ws[16][68];  // [k][col]
    int tid = threadIdx.x;
    int row0 = blockIdx.x * 64;
    int col0 = blockIdx.y * 64;
    int tr = tid >> 4, tc = tid & 15;
    int lr = tid >> 2, lk = (tid & 3) << 2;   // A load: row lr, k-quad lk
    int wk = tid >> 4, wc = (tid & 15) << 2;  // W load: k wk, col-quad wc
    int arow = row0 + lr;
    if (arow > n - 1) arow = n - 1;  // clamp; OOB rows never stored
    float acc[4][4] = {};
    for (int k0 = 0; k0 < 256; k0 += 16) {
        float4 a = *(const float4*)(A + (size_t)arow * 256 + k0 + lk);
        float4 w = *(const float4*)(W + (size_t)(k0 + wk) * M + col0 + wc);
        __syncthreads();
        As[lk + 0][lr] = a.x; As[lk + 1][lr] = a.y;
        As[lk + 2][lr] = a.z; As[lk + 3][lr] = a.w;
        *(float4*)&Ws[wk][wc] = w;
        __syncthreads();
#pragma unroll
        for (int k = 0; k < 16; ++k) {
            float4 av = *(const float4*)&As[k][tr << 2];
            float4 wv = *(const float4*)&Ws[k][tc << 2];
            float avs[4] = {av.x, av.y, av.z, av.w};
            float wvs[4] = {wv.x, wv.y, wv.z, wv.w};
#pragma unroll
            for (int i = 0; i < 4; ++i)
#pragma unroll
                for (int j = 0; j < 4; ++j)
                    acc[i][j] += avs[i] * wvs[j];
        }
    }
    float4 b4 = *(const float4*)(bias + col0 + (tc << 2));
    float bb[4] = {b4.x, b4.y, b4.z, b4.w};
#pragma unroll
    for (int i = 0; i < 4; ++i) {
        int r = row0 + (tr << 2) + i;
        if (r < n) {
            float o[4];
#pragma unroll
            for (int j = 0; j < 4; ++j) {
                float t = acc[i][j] + bb[j];
                if (relu) t = t > 0.f ? t : 0.f;
                o[j] = t;
            }
            *(float4*)(out + (size_t)r * M + col0 + (tc << 2)) = *(float4*)o;
        }
    }
}

extern "C" void kernel_launch(void* const* d_in, const int* in_sizes, int n_in,
                              void* d_out, int out_size, void* d_ws, size_t ws_size,
                              hipStream_t stream) {
    const float* x        = (const float*)d_in[0];
    const int*   ei       = (const int*)d_in[1];   // int32! (harness converts)
    const float* ea       = (const float*)d_in[2];
    const float* w_dense  = (const float*)d_in[3];
    const float* b_dense  = (const float*)d_in[4];
    const float* w_enc    = (const float*)d_in[5];
    const float* b_enc    = (const float*)d_in[6];
    const float* w_mu     = (const float*)d_in[7];
    const float* b_mu     = (const float*)d_in[8];
    const float* w_logstd = (const float*)d_in[9];
    const float* b_logstd = (const float*)d_in[10];

    const int n = in_sizes[0] / 256;  // 100000
    const int E = in_sizes[2];        // 1600000
    const int* row = ei;
    const int* col = ei + E;

    // Workspace carve-up: CSR arrays + one n*256 A-buffer (~117 MB total).
    char* ws = (char*)d_ws;
    size_t off = 0;
    auto alloc = [&](size_t bytes) -> void* {
        void* p = ws + off;
        off = (off + bytes + 255) & ~(size_t)255;
        return p;
    };
    float* deg    = (float*)alloc((size_t)n * 4);       // becomes dinv in-place
    int*   counts = (int*)alloc((size_t)n * 4);
    int*   offs   = (int*)alloc((size_t)(n + 1) * 4);
    int*   cursor = (int*)alloc((size_t)n * 4);
    int*   srow   = (int*)alloc((size_t)E * 4);
    float* sval   = (float*)alloc((size_t)E * 4);
    float* bufA   = (float*)alloc((size_t)n * 256 * 4); // A1, then A2
    (void)ws_size;

    float* hbuf   = (float*)d_out;        // h0, then h1 (dead before final writes)
    float* mu     = (float*)d_out;
    float* logstd = mu + (size_t)n * 128;

    int nb_n = (n + 255) / 256;
    int nb_e = (E + 255) / 256;

    // --- graph preprocessing (structure + normalization) ---
    init_kernel<<<nb_n, 256, 0, stream>>>(deg, counts, n);
    edge_count_kernel<<<nb_e, 256, 0, stream>>>(col, ea, deg, counts, E);
    dinv_kernel<<<nb_n, 256, 0, stream>>>(deg, n);
    scan_kernel<<<1, 1024, 0, stream>>>(counts, offs, cursor, n);
    fill_kernel<<<nb_e, 256, 0, stream>>>(row, col, ea, deg, cursor, srow, sval, E);

    // --- pipeline ---
    matmul_kernel<<<dim3((n + 63) / 64, 4), 256, 0, stream>>>(x, w_dense, b_dense, hbuf, n, 256, 1);
    spmm_kernel<<<(n + 3) / 4, 256, 0, stream>>>(hbuf, srow, sval, offs, deg, bufA, n);
    matmul_kernel<<<dim3((n + 63) / 64, 4), 256, 0, stream>>>(bufA, w_enc, b_enc, hbuf, n, 256, 0);
    spmm_kernel<<<(n + 3) / 4, 256, 0, stream>>>(hbuf, srow, sval, offs, deg, bufA, n);
    matmul_kernel<<<dim3((n + 63) / 64, 2), 256, 0, stream>>>(bufA, w_mu, b_mu, mu, n, 128, 0);
    matmul_kernel<<<dim3((n + 63) / 64, 2), 256, 0, stream>>>(bufA, w_logstd, b_logstd, logstd, n, 128, 0);
}

// Round 3
// 1312.289 us; speedup vs baseline: 1.2066x; 1.2066x over previous
//
#include <hip/hip_runtime.h>

// ---------------------------------------------------------------------------
// Encoder_18365280157999: GCN-VGAE encoder on MI355X (gfx950).
//   h0 = relu(x @ w_dense + b);  A1 = Agg(h0);  h1 = A1 @ w_enc + b
//   A2 = Agg(h1);  mu = A2 @ w_mu + b;  logstd = A2 @ w_logstd + b
// (Agg commutes with the right-matmul, so 2 aggregations instead of 3.)
//
// R3: bf16 storage for activations (halves SpMM gather traffic; 51MB h is
// L3-resident), MFMA GEMMs with split-precision W (W_hi+W_lo bf16, fp32
// accum; A single bf16 -> est absmax ~7e-3 vs 1.8e-2 threshold), and a
// wave-shuffle scan (4 barriers/chunk vs 20).
//
// d_out doubles as activation storage (both halves dead before final write):
//   lower half: xb (bf16 x), then h1, then mu(fp32)
//   upper half: h0, then logstd(fp32)
// ws: CSR arrays + bf16 A-buffer + W splits ~ 67 MB (proven >=117 avail).
// ---------------------------------------------------------------------------

typedef short bf16x8 __attribute__((ext_vector_type(8)));
typedef float f32x4 __attribute__((ext_vector_type(4)));

static __device__ __forceinline__ unsigned int f2bf(float f) {
    unsigned int u = __float_as_uint(f);
    return ((u + 0x7fffu + ((u >> 16) & 1u)) >> 16) & 0xffffu;  // RNE
}
static __device__ __forceinline__ float bf2f(unsigned int us) {
    return __uint_as_float(us << 16);
}

// ---------------- preprocessing ----------------

__global__ __launch_bounds__(256) void init_kernel(float* deg, int* counts, int n) {
    int i = blockIdx.x * 256 + threadIdx.x;
    if (i < n) { deg[i] = 1.0f; counts[i] = 0; }
}

__global__ __launch_bounds__(256) void edge_count_kernel(const int* __restrict__ col,
                                                         const float* __restrict__ ew,
                                                         float* __restrict__ deg,
                                                         int* __restrict__ counts, int E) {
    int e = blockIdx.x * 256 + threadIdx.x;
    if (e < E) {
        int c = col[e];
        atomicAdd(&deg[c], ew[e]);
        atomicAdd(&counts[c], 1);
    }
}

__global__ __launch_bounds__(256) void dinv_kernel(float* deg, int n) {
    int i = blockIdx.x * 256 + threadIdx.x;
    if (i < n) deg[i] = rsqrtf(deg[i]);  // deg >= 1 (self-loop weight 1)
}

// Single-block scan, wave-shuffle based: 4 barriers per 1024-chunk.
__global__ __launch_bounds__(1024) void scan_kernel(const int* __restrict__ counts,
                                                    int* __restrict__ offsets,
                                                    int* __restrict__ cursor, int n) {
    __shared__ int wsum[16];
    __shared__ int tot;
    __shared__ int carry_s;
    int tid = threadIdx.x, lane = tid & 63, wv = tid >> 6;
    if (tid == 0) carry_s = 0;
    __syncthreads();
    for (int base = 0; base < n; base += 1024) {
        int i = base + tid;
        int v = (i < n) ? counts[i] : 0;
        int s = v;
#pragma unroll
        for (int off = 1; off < 64; off <<= 1) {
            int t = __shfl_up(s, off, 64);
            if (lane >= off) s += t;
        }
        if (lane == 63) wsum[wv] = s;  // inclusive wave total
        __syncthreads();
        if (wv == 0 && lane < 16) {
            int w = wsum[lane];
            int ss = w;
#pragma unroll
            for (int off = 1; off < 16; off <<= 1) {
                int t = __shfl_up(ss, off, 64);
                if (lane >= off) ss += t;
            }
            wsum[lane] = ss - w;  // exclusive prefix of wave sums
            if (lane == 15) tot = ss;
        }
        __syncthreads();
        int excl = carry_s + wsum[wv] + s - v;
        if (i < n) { offsets[i] = excl; cursor[i] = excl; }
        __syncthreads();
        if (tid == 0) carry_s += tot;
        __syncthreads();
    }
    if (tid == 0) offsets[n] = carry_s;
}

__global__ __launch_bounds__(256) void fill_kernel(const int* __restrict__ row,
                                                   const int* __restrict__ col,
                                                   const float* __restrict__ ew,
                                                   const float* __restrict__ dinv,
                                                   int* __restrict__ cursor,
                                                   int* __restrict__ srow,
                                                   float* __restrict__ sval, int E) {
    int e = blockIdx.x * 256 + threadIdx.x;
    if (e < E) {
        int c = col[e];
        int r = row[e];
        int pos = atomicAdd(&cursor[c], 1);
        srow[pos] = r;
        sval[pos] = dinv[r] * ew[e];  // final dinv[c] applied in spmm epilogue
    }
}

// x (fp32) -> bf16, 4 elems/thread
__global__ __launch_bounds__(256) void cvt_bf16_kernel(const float* __restrict__ in,
                                                       unsigned int* __restrict__ out2,
                                                       int count4) {
    int i = blockIdx.x * 256 + threadIdx.x;
    if (i < count4) {
        float4 v = ((const float4*)in)[i];
        uint2 w;
        w.x = f2bf(v.x) | (f2bf(v.y) << 16);
        w.y = f2bf(v.z) | (f2bf(v.w) << 16);
        ((uint2*)out2)[i] = w;
    }
}

// W [256 x M] fp32 -> transposed split Wt_hi/Wt_lo [M x 256] bf16.
__global__ __launch_bounds__(256) void splitw_kernel(const float* __restrict__ W, int M,
                                                     unsigned short* __restrict__ hi,
                                                     unsigned short* __restrict__ lo) {
    int idx = blockIdx.x * 256 + threadIdx.x;  // idx = c*256 + k
    if (idx < M * 256) {
        int c = idx >> 8, k = idx & 255;
        float w = W[k * M + c];
        unsigned int h = f2bf(w);
        float r = w - bf2f(h);
        hi[idx] = (unsigned short)h;
        lo[idx] = (unsigned short)f2bf(r);
    }
}

// ---------------- SpMM (bf16 gather) ----------------
// out[c] = dinv[c] * ( sum_e sval_e * h[srow_e] + dinv[c]*h[c] ), 256 cols.
// One wave per destination; lane covers 4 cols (uint2 = 4 bf16).
__global__ __launch_bounds__(256) void spmm_kernel(const unsigned short* __restrict__ h,
                                                   const int* __restrict__ srow,
                                                   const float* __restrict__ sval,
                                                   const int* __restrict__ offsets,
                                                   const float* __restrict__ dinv,
                                                   unsigned short* __restrict__ out, int n) {
    int wave = threadIdx.x >> 6;
    int lane = threadIdx.x & 63;
    int c = blockIdx.x * 4 + wave;
    if (c >= n) return;
    const uint2* __restrict__ h2 = (const uint2*)h;
    float di = dinv[c];
    int beg = offsets[c], end = offsets[c + 1];
    uint2 v = h2[(size_t)c * 64 + lane];
    float a0 = di * __uint_as_float(v.x << 16);
    float a1 = di * __uint_as_float(v.x & 0xffff0000u);
    float a2 = di * __uint_as_float(v.y << 16);
    float a3 = di * __uint_as_float(v.y & 0xffff0000u);
    for (int e = beg; e < end; ++e) {
        int r = srow[e];
        float s = sval[e];
        uint2 u = h2[(size_t)r * 64 + lane];
        a0 += s * __uint_as_float(u.x << 16);
        a1 += s * __uint_as_float(u.x & 0xffff0000u);
        a2 += s * __uint_as_float(u.y << 16);
        a3 += s * __uint_as_float(u.y & 0xffff0000u);
    }
    uint2 w;
    w.x = f2bf(di * a0) | (f2bf(di * a1) << 16);
    w.y = f2bf(di * a2) | (f2bf(di * a3) << 16);
    ((uint2*)out)[(size_t)c * 64 + lane] = w;
}

// ---------------- MFMA GEMM ----------------
// C[n x M] = A[n x 256](bf16) @ (W_hi + W_lo)[256 x M] + bias.
// Wt_hi/Wt_lo stored transposed [M x 256] so B-frags are contiguous b128.
// Block: 256 thr = 4 waves; tile 128x128, BK=32; wave quadrant 64x64 =
// 4x4 MFMA(16x16x32) tiles; split-W -> 32 MFMAs/wave/K-step.
// flags: 1 = relu, 2 = bf16 output.
#define LDST 40  // LDS row stride in bf16 elems (32 + 8 pad; keeps b128 align)

__global__ __launch_bounds__(256) void mfma_gemm_kernel(const unsigned short* __restrict__ A,
                                                        const unsigned short* __restrict__ Wh,
                                                        const unsigned short* __restrict__ Wl,
                                                        const float* __restrict__ bias,
                                                        void* __restrict__ outp,
                                                        int n, int M, int flags) {
    __shared__ __align__(16) short As[128 * LDST];
    __shared__ __align__(16) short Bh[128 * LDST];
    __shared__ __align__(16) short Bl[128 * LDST];
    int tid = threadIdx.x;
    int r0 = blockIdx.x * 128;
    int c0 = blockIdx.y * 128;
    int lane = tid & 63, wave = tid >> 6;
    int wr = wave & 1, wc = wave >> 1;
    int l16 = lane & 15, quad = lane >> 4;

    f32x4 acc[4][4];
#pragma unroll
    for (int i = 0; i < 4; ++i)
#pragma unroll
        for (int j = 0; j < 4; ++j) acc[i][j] = (f32x4)0.0f;

    // staging: 16B granules; granule g: row g>>2, quarter q = g&3
    int row_a = tid >> 1;               // not used; explicit per-s below
    (void)row_a;

    for (int k0 = 0; k0 < 256; k0 += 32) {
        uint4 av[2], bhv[2], blv[2];
#pragma unroll
        for (int s = 0; s < 2; ++s) {
            int g = tid + s * 256;
            int row = g >> 2, q = g & 3;
            int gr = r0 + row; if (gr > n - 1) gr = n - 1;
            av[s]  = *(const uint4*)(A  + (size_t)gr * 256 + k0 + q * 8);
            int gc = c0 + row;  // M % 128 == 0, always in range
            bhv[s] = *(const uint4*)(Wh + (size_t)gc * 256 + k0 + q * 8);
            blv[s] = *(const uint4*)(Wl + (size_t)gc * 256 + k0 + q * 8);
        }
        __syncthreads();
#pragma unroll
        for (int s = 0; s < 2; ++s) {
            int g = tid + s * 256;
            int row = g >> 2, q = g & 3;
            *(uint4*)(As + row * LDST + q * 8) = av[s];
            *(uint4*)(Bh + row * LDST + q * 8) = bhv[s];
            *(uint4*)(Bl + row * LDST + q * 8) = blv[s];
        }
        __syncthreads();
        bf16x8 af[4], bh[4], bl[4];
#pragma unroll
        for (int t = 0; t < 4; ++t) {
            af[t] = *(const bf16x8*)(As + (64 * wr + 16 * t + l16) * LDST + quad * 8);
            bh[t] = *(const bf16x8*)(Bh + (64 * wc + 16 * t + l16) * LDST + quad * 8);
            bl[t] = *(const bf16x8*)(Bl + (64 * wc + 16 * t + l16) * LDST + quad * 8);
        }
#pragma unroll
        for (int rt = 0; rt < 4; ++rt)
#pragma unroll
            for (int ct = 0; ct < 4; ++ct) {
                acc[rt][ct] = __builtin_amdgcn_mfma_f32_16x16x32_bf16(af[rt], bh[ct], acc[rt][ct], 0, 0, 0);
                acc[rt][ct] = __builtin_amdgcn_mfma_f32_16x16x32_bf16(af[rt], bl[ct], acc[rt][ct], 0, 0, 0);
            }
    }

    int relu = flags & 1, obf = flags & 2;
#pragma unroll
    for (int ct = 0; ct < 4; ++ct) {
        int col = c0 + 64 * wc + 16 * ct + l16;
        float b = bias[col];
#pragma unroll
        for (int rt = 0; rt < 4; ++rt) {
            int rbase = r0 + 64 * wr + 16 * rt + quad * 4;
#pragma unroll
            for (int i = 0; i < 4; ++i) {
                int r = rbase + i;
                if (r < n) {
                    float v = acc[rt][ct][i] + b;
                    if (relu) v = fmaxf(v, 0.0f);
                    if (obf) ((unsigned short*)outp)[(size_t)r * M + col] = (unsigned short)f2bf(v);
                    else     ((float*)outp)[(size_t)r * M + col] = v;
                }
            }
        }
    }
}

// ---------------- launch ----------------

extern "C" void kernel_launch(void* const* d_in, const int* in_sizes, int n_in,
                              void* d_out, int out_size, void* d_ws, size_t ws_size,
                              hipStream_t stream) {
    const float* x        = (const float*)d_in[0];
    const int*   ei       = (const int*)d_in[1];   // int32 (harness converts)
    const float* ea       = (const float*)d_in[2];
    const float* w_dense  = (const float*)d_in[3];
    const float* b_dense  = (const float*)d_in[4];
    const float* w_enc    = (const float*)d_in[5];
    const float* b_enc    = (const float*)d_in[6];
    const float* w_mu     = (const float*)d_in[7];
    const float* b_mu     = (const float*)d_in[8];
    const float* w_logstd = (const float*)d_in[9];
    const float* b_logstd = (const float*)d_in[10];

    const int n = in_sizes[0] / 256;  // 100000
    const int E = in_sizes[2];        // 1600000
    const int* row = ei;
    const int* col = ei + E;

    char* ws = (char*)d_ws;
    size_t off = 0;
    auto alloc = [&](size_t bytes) -> void* {
        void* p = ws + off;
        off = (off + bytes + 255) & ~(size_t)255;
        return p;
    };
    float* deg    = (float*)alloc((size_t)n * 4);
    int*   counts = (int*)alloc((size_t)n * 4);
    int*   offs   = (int*)alloc((size_t)(n + 1) * 4);
    int*   cursor = (int*)alloc((size_t)n * 4);
    int*   srow   = (int*)alloc((size_t)E * 4);
    float* sval   = (float*)alloc((size_t)E * 4);
    unsigned short* Ab   = (unsigned short*)alloc((size_t)n * 256 * 2);  // A1 then A2 (bf16)
    unsigned short* wd_h = (unsigned short*)alloc(256 * 256 * 2);
    unsigned short* wd_l = (unsigned short*)alloc(256 * 256 * 2);
    unsigned short* we_h = (unsigned short*)alloc(256 * 256 * 2);
    unsigned short* we_l = (unsigned short*)alloc(256 * 256 * 2);
    unsigned short* wm_h = (unsigned short*)alloc(128 * 256 * 2);
    unsigned short* wm_l = (unsigned short*)alloc(128 * 256 * 2);
    unsigned short* wg_h = (unsigned short*)alloc(128 * 256 * 2);
    unsigned short* wg_l = (unsigned short*)alloc(128 * 256 * 2);
    (void)ws_size;

    // d_out as activation scratch: lower half / upper half (51.2 MB each)
    unsigned short* xb  = (unsigned short*)d_out;                    // bf16 x, then h1
    unsigned short* hb  = (unsigned short*)d_out + (size_t)n * 256;  // h0
    float* mu     = (float*)d_out;                  // over dead h1
    float* logstd = (float*)d_out + (size_t)n * 128;  // over dead h0

    int nb_n = (n + 255) / 256;
    int nb_e = (E + 255) / 256;
    int nrb  = (n + 127) / 128;  // 782

    // preprocessing
    init_kernel<<<nb_n, 256, 0, stream>>>(deg, counts, n);
    edge_count_kernel<<<nb_e, 256, 0, stream>>>(col, ea, deg, counts, E);
    dinv_kernel<<<nb_n, 256, 0, stream>>>(deg, n);
    scan_kernel<<<1, 1024, 0, stream>>>(counts, offs, cursor, n);
    fill_kernel<<<nb_e, 256, 0, stream>>>(row, col, ea, deg, cursor, srow, sval, E);

    // dtype prep
    cvt_bf16_kernel<<<(n * 64 + 255) / 256, 256, 0, stream>>>(x, (unsigned int*)xb, n * 64);
    splitw_kernel<<<256, 256, 0, stream>>>(w_dense, 256, wd_h, wd_l);
    splitw_kernel<<<256, 256, 0, stream>>>(w_enc, 256, we_h, we_l);
    splitw_kernel<<<128, 256, 0, stream>>>(w_mu, 128, wm_h, wm_l);
    splitw_kernel<<<128, 256, 0, stream>>>(w_logstd, 128, wg_h, wg_l);

    // pipeline
    mfma_gemm_kernel<<<dim3(nrb, 2), 256, 0, stream>>>(xb, wd_h, wd_l, b_dense, hb, n, 256, 1 | 2);
    spmm_kernel<<<(n + 3) / 4, 256, 0, stream>>>(hb, srow, sval, offs, deg, Ab, n);
    mfma_gemm_kernel<<<dim3(nrb, 2), 256, 0, stream>>>(Ab, we_h, we_l, b_enc, xb, n, 256, 2);
    spmm_kernel<<<(n + 3) / 4, 256, 0, stream>>>(xb, srow, sval, offs, deg, Ab, n);
    mfma_gemm_kernel<<<dim3(nrb, 1), 256, 0, stream>>>(Ab, wm_h, wm_l, b_mu, mu, n, 128, 0);
    mfma_gemm_kernel<<<dim3(nrb, 1), 256, 0, stream>>>(Ab, wg_h, wg_l, b_logstd, logstd, n, 128, 0);
}

// Round 4
// 921.078 us; speedup vs baseline: 1.7191x; 1.4247x over previous
//
#include <hip/hip_runtime.h>

// ---------------------------------------------------------------------------
// Encoder_18365280157999: GCN-VGAE encoder on MI355X (gfx950).
//   h0 = relu(x @ w_dense + b);  A1 = Agg(h0);  h1 = A1 @ w_enc + b
//   A2 = Agg(h1);  mu = A2 @ w_mu + b;  logstd = A2 @ w_logstd + b
//
// R4: GEMM rewritten to m97 structure: global_load_lds width=16 staging from
// MFMA-fragment-major buffers ([T][K][q][l16][j], 1KB chunk = one wave-load),
// linear lane*16B ds_read_b128 (2-way alias = free). Producers (cvt, spmm,
// splitw) emit fragment layout directly. SpMM: packed uint2 edges + unroll-4
// for MLP. Scan: 3-kernel hierarchical (was single-block serial).
//
// Fragment-major addressing for element (row r, col k) of an [n x 256] bf16:
//   T=r>>4, l=r&15, K=k>>5, q=(k>>3)&3, j=k&7
//   short offset = (T*8+K)*512 + q*128 + l*8 + j       (chunk = 1KB)
// A wave's MFMA A/B fragment (lane = quad*16+l16) is chunk_base + lane*16B.
// ---------------------------------------------------------------------------

typedef short bf16x8 __attribute__((ext_vector_type(8)));
typedef float f32x4 __attribute__((ext_vector_type(4)));

static __device__ __forceinline__ unsigned int f2bf(float f) {
    unsigned int u = __float_as_uint(f);
    return ((u + 0x7fffu + ((u >> 16) & 1u)) >> 16) & 0xffffu;  // RNE
}
static __device__ __forceinline__ float bf2f(unsigned int us) {
    return __uint_as_float(us << 16);
}

static __device__ __forceinline__ void load_lds16(const void* g, void* l) {
    __builtin_amdgcn_global_load_lds(
        (const __attribute__((address_space(1))) unsigned int*)g,
        (__attribute__((address_space(3))) unsigned int*)l, 16, 0, 0);
}

// ---------------- preprocessing ----------------

__global__ __launch_bounds__(256) void init_kernel(float* deg, int* counts, int n) {
    int i = blockIdx.x * 256 + threadIdx.x;
    if (i < n) { deg[i] = 1.0f; counts[i] = 0; }
}

__global__ __launch_bounds__(256) void edge_count_kernel(const int* __restrict__ col,
                                                         const float* __restrict__ ew,
                                                         float* __restrict__ deg,
                                                         int* __restrict__ counts, int E) {
    int e = blockIdx.x * 256 + threadIdx.x;
    if (e < E) {
        int c = col[e];
        atomicAdd(&deg[c], ew[e]);
        atomicAdd(&counts[c], 1);
    }
}

__global__ __launch_bounds__(256) void dinv_kernel(float* deg, int n) {
    int i = blockIdx.x * 256 + threadIdx.x;
    if (i < n) deg[i] = rsqrtf(deg[i]);  // deg >= 1 (self-loop weight 1)
}

// Hierarchical scan, stage A: per-block (1024) local exclusive scan + block sum.
__global__ __launch_bounds__(1024) void scanA_kernel(const int* __restrict__ counts,
                                                     int* __restrict__ offsets,
                                                     int* __restrict__ bsum, int n) {
    __shared__ int wsum[16];
    int tid = threadIdx.x, lane = tid & 63, wv = tid >> 6;
    int i = blockIdx.x * 1024 + tid;
    int v = (i < n) ? counts[i] : 0;
    int s = v;
#pragma unroll
    for (int off = 1; off < 64; off <<= 1) {
        int t = __shfl_up(s, off, 64);
        if (lane >= off) s += t;
    }
    if (lane == 63) wsum[wv] = s;
    __syncthreads();
    if (wv == 0 && lane < 16) {
        int w = wsum[lane];
        int ss = w;
#pragma unroll
        for (int off = 1; off < 16; off <<= 1) {
            int t = __shfl_up(ss, off, 64);
            if (lane >= off) ss += t;
        }
        wsum[lane] = ss - w;
        if (lane == 15 && blockIdx.x * 1024 + 1024 >= 0) bsum[blockIdx.x] = ss;
    }
    __syncthreads();
    if (i < n) offsets[i] = wsum[wv] + s - v;
}

// Stage B: scan the <=128 block sums in one block; write offsets[n]=total.
__global__ __launch_bounds__(128) void scanB_kernel(int* __restrict__ bsum, int nb,
                                                    int* __restrict__ offsets, int n) {
    __shared__ int w0tot;
    int tid = threadIdx.x, lane = tid & 63, wv = tid >> 6;
    int v = (tid < nb) ? bsum[tid] : 0;
    int s = v;
#pragma unroll
    for (int off = 1; off < 64; off <<= 1) {
        int t = __shfl_up(s, off, 64);
        if (lane >= off) s += t;
    }
    if (wv == 0 && lane == 63) w0tot = s;
    __syncthreads();
    int excl = s - v + (wv ? w0tot : 0);
    if (tid < nb) bsum[tid] = excl;
    if (tid == nb - 1) offsets[n] = excl + v;
}

// Stage C: add block prefixes; seed cursor.
__global__ __launch_bounds__(256) void scanC_kernel(int* __restrict__ offsets,
                                                    const int* __restrict__ bsum,
                                                    int* __restrict__ cursor, int n) {
    int i = blockIdx.x * 256 + threadIdx.x;
    if (i < n) {
        int o = offsets[i] + bsum[i >> 10];
        offsets[i] = o;
        cursor[i] = o;
    }
}

// Fill CSR: packed (srow, sval) 8B stores.
__global__ __launch_bounds__(256) void fill_kernel(const int* __restrict__ row,
                                                   const int* __restrict__ col,
                                                   const float* __restrict__ ew,
                                                   const float* __restrict__ dinv,
                                                   int* __restrict__ cursor,
                                                   uint2* __restrict__ edges, int E) {
    int e = blockIdx.x * 256 + threadIdx.x;
    if (e < E) {
        int c = col[e];
        int r = row[e];
        int pos = atomicAdd(&cursor[c], 1);
        uint2 p;
        p.x = (unsigned int)r;
        p.y = __float_as_uint(dinv[r] * ew[e]);
        edges[pos] = p;
    }
}

// x (fp32 row-major) -> bf16 fragment-major. One wave per row; lane covers 4 k.
__global__ __launch_bounds__(256) void cvt_frag_kernel(const float* __restrict__ x,
                                                       unsigned short* __restrict__ Af, int n) {
    int g = blockIdx.x * 256 + threadIdx.x;
    int c = g >> 6, lane = g & 63;
    if (c >= n) return;
    float4 v = ((const float4*)x)[(size_t)c * 64 + lane];
    uint2 w;
    w.x = f2bf(v.x) | (f2bf(v.y) << 16);
    w.y = f2bf(v.z) | (f2bf(v.w) << 16);
    int T = c >> 4, l = c & 15;
    size_t idx8 = (size_t)T * 1024 + (size_t)((lane >> 3)) * 128 + ((lane >> 1) & 3) * 32 + l * 2 + (lane & 1);
    ((uint2*)Af)[idx8] = w;
}

// W [256 x M] fp32 -> fragment-major split Wh/Wl [Tc][K][q][l][j] bf16.
__global__ __launch_bounds__(256) void splitw_kernel(const float* __restrict__ W, int M,
                                                     unsigned short* __restrict__ hi,
                                                     unsigned short* __restrict__ lo) {
    int idx = blockIdx.x * 256 + threadIdx.x;  // idx = c*256 + k
    if (idx < M * 256) {
        int c = idx >> 8, k = idx & 255;
        float w = W[k * M + c];
        unsigned int h = f2bf(w);
        float r = w - bf2f(h);
        int T = c >> 4, l = c & 15, K = k >> 5, q = (k >> 3) & 3, j = k & 7;
        size_t o = (size_t)(T * 8 + K) * 512 + q * 128 + l * 8 + j;
        hi[o] = (unsigned short)h;
        lo[o] = (unsigned short)f2bf(r);
    }
}

// ---------------- SpMM (bf16 gather, row-major in, fragment-major out) ------
__global__ __launch_bounds__(256) void spmm_kernel(const unsigned short* __restrict__ h,
                                                   const uint2* __restrict__ edges,
                                                   const int* __restrict__ offsets,
                                                   const float* __restrict__ dinv,
                                                   unsigned short* __restrict__ outf, int n) {
    int wave = threadIdx.x >> 6;
    int lane = threadIdx.x & 63;
    int c = blockIdx.x * 4 + wave;
    if (c >= n) return;
    const uint2* __restrict__ h2 = (const uint2*)h;
    float di = dinv[c];
    int beg = offsets[c], end = offsets[c + 1];
    uint2 v = h2[(size_t)c * 64 + lane];
    float a0 = di * __uint_as_float(v.x << 16);
    float a1 = di * __uint_as_float(v.x & 0xffff0000u);
    float a2 = di * __uint_as_float(v.y << 16);
    float a3 = di * __uint_as_float(v.y & 0xffff0000u);
    int e = beg;
    for (; e + 4 <= end; e += 4) {
        uint2 e0 = edges[e], e1 = edges[e + 1], e2 = edges[e + 2], e3 = edges[e + 3];
        uint2 u0 = h2[(size_t)e0.x * 64 + lane];
        uint2 u1 = h2[(size_t)e1.x * 64 + lane];
        uint2 u2 = h2[(size_t)e2.x * 64 + lane];
        uint2 u3 = h2[(size_t)e3.x * 64 + lane];
        float s0 = __uint_as_float(e0.y), s1 = __uint_as_float(e1.y);
        float s2 = __uint_as_float(e2.y), s3 = __uint_as_float(e3.y);
        a0 += s0 * __uint_as_float(u0.x << 16);
        a1 += s0 * __uint_as_float(u0.x & 0xffff0000u);
        a2 += s0 * __uint_as_float(u0.y << 16);
        a3 += s0 * __uint_as_float(u0.y & 0xffff0000u);
        a0 += s1 * __uint_as_float(u1.x << 16);
        a1 += s1 * __uint_as_float(u1.x & 0xffff0000u);
        a2 += s1 * __uint_as_float(u1.y << 16);
        a3 += s1 * __uint_as_float(u1.y & 0xffff0000u);
        a0 += s2 * __uint_as_float(u2.x << 16);
        a1 += s2 * __uint_as_float(u2.x & 0xffff0000u);
        a2 += s2 * __uint_as_float(u2.y << 16);
        a3 += s2 * __uint_as_float(u2.y & 0xffff0000u);
        a0 += s3 * __uint_as_float(u3.x << 16);
        a1 += s3 * __uint_as_float(u3.x & 0xffff0000u);
        a2 += s3 * __uint_as_float(u3.y << 16);
        a3 += s3 * __uint_as_float(u3.y & 0xffff0000u);
    }
    for (; e < end; ++e) {
        uint2 ee = edges[e];
        float s = __uint_as_float(ee.y);
        uint2 u = h2[(size_t)ee.x * 64 + lane];
        a0 += s * __uint_as_float(u.x << 16);
        a1 += s * __uint_as_float(u.x & 0xffff0000u);
        a2 += s * __uint_as_float(u.y << 16);
        a3 += s * __uint_as_float(u.y & 0xffff0000u);
    }
    uint2 w;
    w.x = f2bf(di * a0) | (f2bf(di * a1) << 16);
    w.y = f2bf(di * a2) | (f2bf(di * a3) << 16);
    int T = c >> 4, l = c & 15;
    size_t idx8 = (size_t)T * 1024 + (size_t)((lane >> 3)) * 128 + ((lane >> 1) & 3) * 32 + l * 2 + (lane & 1);
    ((uint2*)outf)[idx8] = w;
}

// ---------------- MFMA GEMM (m97 structure) ----------------
// C[n x M] = A[n x 256](frag bf16) @ (Wh + Wl)(frag bf16) + bias.
// 128x128 tile, BK=32; 4 waves; global_load_lds 16B staging, 24 chunks/k-step.
// flags: 1 = relu, 2 = bf16 output.
__global__ __launch_bounds__(256) void mfma_gemm_kernel(const unsigned short* __restrict__ Af,
                                                        const unsigned short* __restrict__ Wh,
                                                        const unsigned short* __restrict__ Wl,
                                                        const float* __restrict__ bias,
                                                        void* __restrict__ outp,
                                                        int n, int M, int flags) {
    __shared__ short lds[12288];  // shorts: A 0..4095 | Bh 4096..8191 | Bl 8192..12287
    int tid = threadIdx.x, lane = tid & 63, wave = tid >> 6;
    int wr = wave & 1, wc = wave >> 1;
    int l16 = lane & 15, quad = lane >> 4;
    int T0 = blockIdx.x * 8;   // A tile base (rows /16)
    int Tc0 = blockIdx.y * 8;  // B tile base (cols /16)

    f32x4 acc[4][4];
#pragma unroll
    for (int i = 0; i < 4; ++i)
#pragma unroll
        for (int j = 0; j < 4; ++j) acc[i][j] = (f32x4)0.0f;

    for (int K = 0; K < 8; ++K) {
#pragma unroll
        for (int j = 0; j < 6; ++j) {
            int cid = wave * 6 + j;
            const unsigned short* g;
            if (cid < 8)       g = Af + ((size_t)(T0 + cid) * 8 + K) * 512;
            else if (cid < 16) g = Wh + ((size_t)(Tc0 + cid - 8) * 8 + K) * 512;
            else               g = Wl + ((size_t)(Tc0 + cid - 16) * 8 + K) * 512;
            load_lds16(g + (size_t)lane * 8, lds + cid * 512);
        }
        __syncthreads();
        bf16x8 af[4], bh[4], bl[4];
#pragma unroll
        for (int t = 0; t < 4; ++t) {
            af[t] = *(const bf16x8*)(lds + (4 * wr + t) * 512 + lane * 8);
            bh[t] = *(const bf16x8*)(lds + 4096 + (4 * wc + t) * 512 + lane * 8);
            bl[t] = *(const bf16x8*)(lds + 8192 + (4 * wc + t) * 512 + lane * 8);
        }
#pragma unroll
        for (int rt = 0; rt < 4; ++rt)
#pragma unroll
            for (int ct = 0; ct < 4; ++ct) {
                acc[rt][ct] = __builtin_amdgcn_mfma_f32_16x16x32_bf16(af[rt], bh[ct], acc[rt][ct], 0, 0, 0);
                acc[rt][ct] = __builtin_amdgcn_mfma_f32_16x16x32_bf16(af[rt], bl[ct], acc[rt][ct], 0, 0, 0);
            }
        __syncthreads();
    }

    int relu = flags & 1, obf = flags & 2;
    int r0 = T0 * 16, c0 = Tc0 * 16;
#pragma unroll
    for (int ct = 0; ct < 4; ++ct) {
        int col = c0 + 64 * wc + 16 * ct + l16;
        float b = bias[col];
#pragma unroll
        for (int rt = 0; rt < 4; ++rt) {
            int rbase = r0 + 64 * wr + 16 * rt + quad * 4;
#pragma unroll
            for (int i = 0; i < 4; ++i) {
                int r = rbase + i;
                if (r < n) {
                    float v = acc[rt][ct][i] + b;
                    if (relu) v = fmaxf(v, 0.0f);
                    if (obf) ((unsigned short*)outp)[(size_t)r * M + col] = (unsigned short)f2bf(v);
                    else     ((float*)outp)[(size_t)r * M + col] = v;
                }
            }
        }
    }
}

// ---------------- launch ----------------

extern "C" void kernel_launch(void* const* d_in, const int* in_sizes, int n_in,
                              void* d_out, int out_size, void* d_ws, size_t ws_size,
                              hipStream_t stream) {
    const float* x        = (const float*)d_in[0];
    const int*   ei       = (const int*)d_in[1];   // int32 (harness converts)
    const float* ea       = (const float*)d_in[2];
    const float* w_dense  = (const float*)d_in[3];
    const float* b_dense  = (const float*)d_in[4];
    const float* w_enc    = (const float*)d_in[5];
    const float* b_enc    = (const float*)d_in[6];
    const float* w_mu     = (const float*)d_in[7];
    const float* b_mu     = (const float*)d_in[8];
    const float* w_logstd = (const float*)d_in[9];
    const float* b_logstd = (const float*)d_in[10];

    const int n = in_sizes[0] / 256;  // 100000 (divisible by 16)
    const int E = in_sizes[2];        // 1600000
    const int* row = ei;
    const int* col = ei + E;

    char* ws = (char*)d_ws;
    size_t off = 0;
    auto alloc = [&](size_t bytes) -> void* {
        void* p = ws + off;
        off = (off + bytes + 255) & ~(size_t)255;
        return p;
    };
    const int nTile = (n + 127) / 128;        // 782 row-blocks
    const int nTpad = nTile * 8;              // 6256 T-chunks (pad: garbage ok, never stored)
    float* deg    = (float*)alloc((size_t)n * 4);
    int*   counts = (int*)alloc((size_t)n * 4);
    int*   offs   = (int*)alloc((size_t)(n + 1) * 4);
    int*   cursor = (int*)alloc((size_t)n * 4);
    int*   bsum   = (int*)alloc(128 * 4);
    uint2* edges  = (uint2*)alloc((size_t)E * 8);
    unsigned short* Af   = (unsigned short*)alloc((size_t)nTpad * 8192);  // frag activations
    unsigned short* wd_h = (unsigned short*)alloc(256 * 256 * 2);
    unsigned short* wd_l = (unsigned short*)alloc(256 * 256 * 2);
    unsigned short* we_h = (unsigned short*)alloc(256 * 256 * 2);
    unsigned short* we_l = (unsigned short*)alloc(256 * 256 * 2);
    unsigned short* wm_h = (unsigned short*)alloc(128 * 256 * 2);
    unsigned short* wm_l = (unsigned short*)alloc(128 * 256 * 2);
    unsigned short* wg_h = (unsigned short*)alloc(128 * 256 * 2);
    unsigned short* wg_l = (unsigned short*)alloc(128 * 256 * 2);
    (void)ws_size;

    // d_out doubles as row-major activation storage (dead before final writes)
    unsigned short* h1b = (unsigned short*)d_out;                    // lower: h1, then mu
    unsigned short* h0b = (unsigned short*)d_out + (size_t)n * 256;  // upper: h0, then logstd
    float* mu     = (float*)d_out;
    float* logstd = (float*)d_out + (size_t)n * 128;

    int nb_n = (n + 255) / 256;
    int nb_e = (E + 255) / 256;
    int nb_s = (n + 1023) / 1024;  // 98 scan blocks

    // graph preprocessing
    init_kernel<<<nb_n, 256, 0, stream>>>(deg, counts, n);
    edge_count_kernel<<<nb_e, 256, 0, stream>>>(col, ea, deg, counts, E);
    dinv_kernel<<<nb_n, 256, 0, stream>>>(deg, n);
    scanA_kernel<<<nb_s, 1024, 0, stream>>>(counts, offs, bsum, n);
    scanB_kernel<<<1, 128, 0, stream>>>(bsum, nb_s, offs, n);
    scanC_kernel<<<nb_n, 256, 0, stream>>>(offs, bsum, cursor, n);
    fill_kernel<<<nb_e, 256, 0, stream>>>(row, col, ea, deg, cursor, edges, E);

    // dtype/layout prep
    cvt_frag_kernel<<<(n * 64 + 255) / 256, 256, 0, stream>>>(x, Af, n);
    splitw_kernel<<<256, 256, 0, stream>>>(w_dense, 256, wd_h, wd_l);
    splitw_kernel<<<256, 256, 0, stream>>>(w_enc, 256, we_h, we_l);
    splitw_kernel<<<128, 256, 0, stream>>>(w_mu, 128, wm_h, wm_l);
    splitw_kernel<<<128, 256, 0, stream>>>(w_logstd, 128, wg_h, wg_l);

    // pipeline
    mfma_gemm_kernel<<<dim3(nTile, 2), 256, 0, stream>>>(Af, wd_h, wd_l, b_dense, h0b, n, 256, 1 | 2);
    spmm_kernel<<<(n + 3) / 4, 256, 0, stream>>>(h0b, edges, offs, deg, Af, n);
    mfma_gemm_kernel<<<dim3(nTile, 2), 256, 0, stream>>>(Af, we_h, we_l, b_enc, h1b, n, 256, 2);
    spmm_kernel<<<(n + 3) / 4, 256, 0, stream>>>(h1b, edges, offs, deg, Af, n);
    mfma_gemm_kernel<<<dim3(nTile, 1), 256, 0, stream>>>(Af, wm_h, wm_l, b_mu, mu, n, 128, 0);
    mfma_gemm_kernel<<<dim3(nTile, 1), 256, 0, stream>>>(Af, wg_h, wg_l, b_logstd, logstd, n, 128, 0);
}